// Round 8
// baseline (2126.507 us; speedup 1.0000x reference)
//
#include <hip/hip_runtime.h>
#include <math.h>

#define NG 1024   // graphs per side
#define FIN 32
#define FOUT 64
#define BSH 8                 // bucket shift: 256 nodes per bucket
#define BNODES 256

// ---------------- degree: deg[dst] += 1 per edge (self-loop added later) ----
__global__ void k_degree(const int* __restrict__ ei1, const int* __restrict__ ei2,
                         int E, unsigned* __restrict__ deg, int N) {
    const int side = blockIdx.y;
    const int* ei = side ? ei2 : ei1;
    unsigned* d = deg + (size_t)side * N;
    int e = blockIdx.x * blockDim.x + threadIdx.x;
    if (e < E) atomicAdd(&d[ei[E + e]], 1u);
}

// ---------------- bucket sums: bsum[b] = sum(deg[b*256 .. b*256+255]) -------
__global__ void k_bsum(const unsigned* __restrict__ deg,
                       unsigned* __restrict__ bsum, int N, int NB) {
    const int side = blockIdx.y;
    int b = blockIdx.x;
    int n = b * BNODES + threadIdx.x;
    unsigned d = (n < N) ? deg[(size_t)side * N + n] : 0u;
    // 64-lane wave reduce
    for (int off = 32; off; off >>= 1) d += __shfl_down(d, off);
    __shared__ unsigned red[4];
    int w = threadIdx.x >> 6;
    if ((threadIdx.x & 63) == 0) red[w] = d;
    __syncthreads();
    if (threadIdx.x == 0)
        bsum[(size_t)side * NB + b] = red[0] + red[1] + red[2] + red[3];
}

// ---------------- scan bucket sums -> bstart (NB+1), cursor -----------------
__global__ void k_bscan(const unsigned* __restrict__ bsum,
                        unsigned* __restrict__ bstart,
                        unsigned* __restrict__ cursor, int NB) {
    const int side = blockIdx.x;
    __shared__ unsigned s[512];
    int tid = threadIdx.x;
    for (int i = tid; i < 512; i += 256)
        s[i] = (i < NB) ? bsum[(size_t)side * NB + i] : 0u;
    __syncthreads();
    for (int off = 1; off < 512; off <<= 1) {
        unsigned a0 = (tid >= off) ? s[tid - off] : 0u;
        unsigned a1 = (tid + 256 >= off) ? s[tid + 256 - off] : 0u;
        unsigned b0 = s[tid], b1 = s[tid + 256];
        __syncthreads();
        s[tid] = b0 + a0; s[tid + 256] = b1 + a1;
        __syncthreads();
    }
    for (int i = tid; i <= NB; i += 256) {
        unsigned excl = (i == 0) ? 0u : s[i - 1];
        bstart[(size_t)side * (NB + 1) + i] = excl;
        if (i < NB) cursor[(size_t)side * NB + i] = excl;
    }
}

// ---------------- prep: dinv = rsqrt(deg+1); xs = x*dinv --------------------
__global__ void k_prep(const float* __restrict__ x1, const float* __restrict__ x2,
                       const unsigned* __restrict__ deg,
                       float* __restrict__ dinv, float* __restrict__ xs, int N) {
    const int side = blockIdx.y;
    const float* x = side ? x2 : x1;
    int t = blockIdx.x * blockDim.x + threadIdx.x;   // n*8 + q
    int n = t >> 3, q = t & 7;
    if (n >= N) return;
    float di = rsqrtf((float)(deg[(size_t)side * N + n] + 1u));
    if (q == 0) dinv[(size_t)side * N + n] = di;
    size_t base = ((size_t)side * N + n) * FIN + q * 4;
    float4 v = *(const float4*)(x + (size_t)n * FIN + q * 4);
    v.x *= di; v.y *= di; v.z *= di; v.w *= di;
    *(float4*)(xs + base) = v;
}

// ---------------- partition: part[cursor[dst>>8]++] = (src<<8)|(dst&255) ----
__global__ void k_part(const int* __restrict__ ei1, const int* __restrict__ ei2,
                       int E, unsigned* __restrict__ cursor,
                       unsigned* __restrict__ part, int N, int NB) {
    const int side = blockIdx.y;
    const int* ei = side ? ei2 : ei1;
    int e = blockIdx.x * blockDim.x + threadIdx.x;
    if (e >= E) return;
    int s = ei[e], d = ei[E + e];
    unsigned pos = atomicAdd(&cursor[(size_t)side * NB + (d >> BSH)], 1u);
    part[(size_t)side * E + pos] = ((unsigned)s << BSH) | (unsigned)(d & (BNODES - 1));
}

// ---------------- bucket accumulate: LDS accx over 256-node range -----------
// One block per bucket. sacc seeded with self-loop xs rows; 8 lanes/edge
// gather xs[src] float4s and LDS-atomic-accumulate; coalesced writeback.
__global__ void k_bucket(const unsigned* __restrict__ bstart,
                         const unsigned* __restrict__ part,
                         const float* __restrict__ xs,
                         float* __restrict__ accx, int N, int E, int NB) {
    __shared__ float sacc[BNODES * FIN];   // 32 KB
    const int side = blockIdx.y;
    const int b = blockIdx.x;
    const int base = b * BNODES;
    const int tid = threadIdx.x;
    const float* xsS = xs + (size_t)side * N * FIN;

    // seed with self-loop term (zeros for out-of-range tail nodes)
    for (int idx = tid; idx < BNODES * 8; idx += 256) {
        int n = idx >> 3, q = idx & 7;
        float4 v = make_float4(0.f, 0.f, 0.f, 0.f);
        if (base + n < N) v = *(const float4*)(xsS + (size_t)(base + n) * FIN + q * 4);
        *(float4*)&sacc[n * FIN + q * 4] = v;
    }
    __syncthreads();

    unsigned js = bstart[(size_t)side * (NB + 1) + b];
    unsigned je = bstart[(size_t)side * (NB + 1) + b + 1];
    const unsigned* pt = part + (size_t)side * E;
    int q = tid & 7;
    for (unsigned j = js + (tid >> 3); j < je; j += 32) {
        unsigned p = pt[j];
        unsigned s = p >> BSH, d = p & (BNODES - 1);
        float4 v = *(const float4*)(xsS + (size_t)s * FIN + q * 4);
        float* a = &sacc[d * FIN + q * 4];
        atomicAdd(a + 0, v.x);
        atomicAdd(a + 1, v.y);
        atomicAdd(a + 2, v.z);
        atomicAdd(a + 3, v.w);
    }
    __syncthreads();

    int nn = min(BNODES, N - base);
    float* ax = accx + (size_t)side * N * FIN;
    for (int idx = tid; idx < nn * 8; idx += 256) {
        int n = idx >> 3, qq = idx & 7;
        *(float4*)(ax + (size_t)(base + n) * FIN + qq * 4) = *(float4*)&sacc[n * FIN + qq * 4];
    }
}

// ---------------- node out: y = relu(dinv*(accx@W)+b); pool atomics ---------
__global__ void k_nodeout(const float* __restrict__ accx, const float* __restrict__ dinv,
                          const int* __restrict__ b1, const int* __restrict__ b2,
                          const float* __restrict__ Wc, const float* __restrict__ bc,
                          float* __restrict__ gsum, float* __restrict__ gcnt, int N) {
    __shared__ float sW[FIN * FOUT];
    __shared__ float sA[4][FIN];
    const int side = blockIdx.y;
    const int* batch = side ? b2 : b1;
    int tid = threadIdx.x;
    for (int i = tid; i < FIN * FOUT; i += 256) sW[i] = Wc[i];
    int n0 = blockIdx.x * 4;
    if (tid < 128) {
        int nn = n0 + (tid >> 5);
        int f = tid & 31;
        sA[tid >> 5][f] = (nn < N) ? accx[((size_t)side * N + nn) * FIN + f] : 0.f;
    }
    __syncthreads();
    int local = tid >> 6;        // node within block, 0..3
    int f = tid & 63;            // output feature
    int n = n0 + local;
    if (n < N) {
        float acc = 0.f;
#pragma unroll
        for (int i = 0; i < FIN; i++) acc += sA[local][i] * sW[i * FOUT + f];
        float y = fmaxf(dinv[(size_t)side * N + n] * acc + bc[f], 0.f);
        int b = batch[n];
        atomicAdd(&gsum[(((size_t)side * NG) + b) * FOUT + f], y);
        if (f == 0) atomicAdd(&gcnt[(size_t)side * NG + b], 1.f);
    }
}

// ---------------- MLP head: 128->64->32->16->1 + sigmoid --------------------
__global__ void k_mlp(const float* __restrict__ gsum, const float* __restrict__ gcnt,
                      const float* __restrict__ W1, const float* __restrict__ bb1,
                      const float* __restrict__ W2, const float* __restrict__ bb2,
                      const float* __restrict__ W3, const float* __restrict__ bb3,
                      const float* __restrict__ W4, const float* __restrict__ bb4,
                      float* __restrict__ out) {
    __shared__ float h[128], h1[64], h2[32], h3[16];
    int g = blockIdx.x, tid = threadIdx.x;
    int side = tid >> 6, f = tid & 63;
    float c = fmaxf(gcnt[(size_t)side * NG + g], 1.f);
    h[tid] = gsum[(((size_t)side * NG) + g) * FOUT + f] / c;
    __syncthreads();
    if (tid < 64) {
        float a = bb1[tid];
#pragma unroll 8
        for (int i = 0; i < 128; i++) a += h[i] * W1[i * 64 + tid];
        h1[tid] = fmaxf(a, 0.f);
    }
    __syncthreads();
    if (tid < 32) {
        float a = bb2[tid];
#pragma unroll 8
        for (int i = 0; i < 64; i++) a += h1[i] * W2[i * 32 + tid];
        h2[tid] = fmaxf(a, 0.f);
    }
    __syncthreads();
    if (tid < 16) {
        float a = bb3[tid];
#pragma unroll 8
        for (int i = 0; i < 32; i++) a += h2[i] * W3[i * 16 + tid];
        h3[tid] = fmaxf(a, 0.f);
    }
    __syncthreads();
    if (tid == 0) {
        float a = bb4[0];
#pragma unroll
        for (int i = 0; i < 16; i++) a += h3[i] * W4[i];
        out[g] = 1.f / (1.f + expf(-a));
    }
}

extern "C" void kernel_launch(void* const* d_in, const int* in_sizes, int n_in,
                              void* d_out, int out_size, void* d_ws, size_t ws_size,
                              hipStream_t stream) {
    const float* x1  = (const float*)d_in[0];
    const int*   ei1 = (const int*)d_in[1];
    const int*   bt1 = (const int*)d_in[2];
    const float* x2  = (const float*)d_in[3];
    const int*   ei2 = (const int*)d_in[4];
    const int*   bt2 = (const int*)d_in[5];
    const float* Wc  = (const float*)d_in[6];
    const float* bc  = (const float*)d_in[7];
    const float* W1  = (const float*)d_in[8];
    const float* bb1 = (const float*)d_in[9];
    const float* W2  = (const float*)d_in[10];
    const float* bb2 = (const float*)d_in[11];
    const float* W3  = (const float*)d_in[12];
    const float* bb3 = (const float*)d_in[13];
    const float* W4  = (const float*)d_in[14];
    const float* bb4 = (const float*)d_in[15];

    const int N = in_sizes[0] / FIN;     // 100000
    const int E = in_sizes[1] / 2;       // 1600000
    const int NB = (N + BNODES - 1) >> BSH;   // 391 buckets/side

    // workspace layout (4-byte units):
    // deg(2N) | gsum(2*NG*64) | gcnt(2*NG)   <-- zeroed
    // dinv(2N) | xs(64N) | accx(64N) | bsum(2NB) | bstart(2(NB+1)) | cursor(2NB) | part(2E)
    unsigned* deg = (unsigned*)d_ws;
    float* gsum = (float*)(deg + 2 * (size_t)N);
    float* gcnt = gsum + 2 * (size_t)NG * FOUT;
    float* dinv = gcnt + 2 * (size_t)NG;
    float* xs   = dinv + 2 * (size_t)N;
    float* accx = xs + 2 * (size_t)N * FIN;
    unsigned* bsum   = (unsigned*)(accx + 2 * (size_t)N * FIN);
    unsigned* bstart = bsum + 2 * (size_t)NB;
    unsigned* cursor = bstart + 2 * (size_t)(NB + 1);
    unsigned* part   = cursor + 2 * (size_t)NB;

    size_t zbytes = (2 * (size_t)N + 2 * (size_t)NG * FOUT + 2 * (size_t)NG) * 4;
    hipMemsetAsync(d_ws, 0, zbytes, stream);

    dim3 blk(256);
    k_degree<<<dim3((E + 255) / 256, 2), blk, 0, stream>>>(ei1, ei2, E, deg, N);
    k_bsum  <<<dim3(NB, 2), blk, 0, stream>>>(deg, bsum, N, NB);
    k_bscan <<<dim3(2), blk, 0, stream>>>(bsum, bstart, cursor, NB);
    k_prep  <<<dim3((N * 8 + 255) / 256, 2), blk, 0, stream>>>(x1, x2, deg, dinv, xs, N);
    k_part  <<<dim3((E + 255) / 256, 2), blk, 0, stream>>>(ei1, ei2, E, cursor, part, N, NB);
    k_bucket<<<dim3(NB, 2), blk, 0, stream>>>(bstart, part, xs, accx, N, E, NB);
    k_nodeout<<<dim3((N + 3) / 4, 2), blk, 0, stream>>>(accx, dinv, bt1, bt2, Wc, bc, gsum, gcnt, N);
    k_mlp<<<NG, 128, 0, stream>>>(gsum, gcnt, W1, bb1, W2, bb2, W3, bb3, W4, bb4, (float*)d_out);
}

// Round 9
// 1190.174 us; speedup vs baseline: 1.7867x; 1.7867x over previous
//
#include <hip/hip_runtime.h>
#include <math.h>

#define NG 1024   // graphs per side
#define FIN 32
#define FOUT 64
#define BSH 8                 // bucket shift: 256 nodes per bucket
#define BNODES 256
#define CHUNK 8192            // edges per k_part2 block

// ---------------- degree: deg[dst] += 1 per edge (self-loop added later) ----
__global__ void k_degree(const int* __restrict__ ei1, const int* __restrict__ ei2,
                         int E, unsigned* __restrict__ deg, int N) {
    const int side = blockIdx.y;
    const int* ei = side ? ei2 : ei1;
    unsigned* d = deg + (size_t)side * N;
    int e = blockIdx.x * blockDim.x + threadIdx.x;
    if (e < E) atomicAdd(&d[ei[E + e]], 1u);
}

// ---------------- bucket sums: bsum[b] = sum(deg[b*256 .. b*256+255]) -------
__global__ void k_bsum(const unsigned* __restrict__ deg,
                       unsigned* __restrict__ bsum, int N, int NB) {
    const int side = blockIdx.y;
    int b = blockIdx.x;
    int n = b * BNODES + threadIdx.x;
    unsigned d = (n < N) ? deg[(size_t)side * N + n] : 0u;
    for (int off = 32; off; off >>= 1) d += __shfl_down(d, off);
    __shared__ unsigned red[4];
    int w = threadIdx.x >> 6;
    if ((threadIdx.x & 63) == 0) red[w] = d;
    __syncthreads();
    if (threadIdx.x == 0)
        bsum[(size_t)side * NB + b] = red[0] + red[1] + red[2] + red[3];
}

// ---------------- scan bucket sums -> bstart (NB+1), cursor -----------------
__global__ void k_bscan(const unsigned* __restrict__ bsum,
                        unsigned* __restrict__ bstart,
                        unsigned* __restrict__ cursor, int NB) {
    const int side = blockIdx.x;
    __shared__ unsigned s[512];
    int tid = threadIdx.x;
    for (int i = tid; i < 512; i += 256)
        s[i] = (i < NB) ? bsum[(size_t)side * NB + i] : 0u;
    __syncthreads();
    for (int off = 1; off < 512; off <<= 1) {
        unsigned a0 = (tid >= off) ? s[tid - off] : 0u;
        unsigned a1 = (tid + 256 >= off) ? s[tid + 256 - off] : 0u;
        unsigned b0 = s[tid], b1 = s[tid + 256];
        __syncthreads();
        s[tid] = b0 + a0; s[tid + 256] = b1 + a1;
        __syncthreads();
    }
    for (int i = tid; i <= NB; i += 256) {
        unsigned excl = (i == 0) ? 0u : s[i - 1];
        bstart[(size_t)side * (NB + 1) + i] = excl;
        if (i < NB) cursor[(size_t)side * NB + i] = excl;
    }
}

// ---------------- prep: dinv = rsqrt(deg+1); xs = x*dinv --------------------
__global__ void k_prep(const float* __restrict__ x1, const float* __restrict__ x2,
                       const unsigned* __restrict__ deg,
                       float* __restrict__ dinv, float* __restrict__ xs, int N) {
    const int side = blockIdx.y;
    const float* x = side ? x2 : x1;
    int t = blockIdx.x * blockDim.x + threadIdx.x;   // n*8 + q
    int n = t >> 3, q = t & 7;
    if (n >= N) return;
    float di = rsqrtf((float)(deg[(size_t)side * N + n] + 1u));
    if (q == 0) dinv[(size_t)side * N + n] = di;
    size_t base = ((size_t)side * N + n) * FIN + q * 4;
    float4 v = *(const float4*)(x + (size_t)n * FIN + q * 4);
    v.x *= di; v.y *= di; v.z *= di; v.w *= di;
    *(float4*)(xs + base) = v;
}

// ---------------- partition, block-aggregated (LDS-staged binning) ----------
// Per block: LDS histogram of its 8192 edges over NB buckets; ONE global
// atomicAdd per (block,bucket) to reserve a contiguous chunk; LDS-cursor
// scatter of packed entries into the chunk. Global atomics: 3.2M -> ~150k.
__global__ void k_part2(const int* __restrict__ ei1, const int* __restrict__ ei2,
                        int E, unsigned* __restrict__ cursor,
                        unsigned* __restrict__ part, int NB) {
    __shared__ unsigned hist[512];
    __shared__ unsigned bofs[512];
    const int side = blockIdx.y;
    const int* ei = side ? ei2 : ei1;
    const int* srcA = ei;
    const int* dstA = ei + E;
    const int cbase = blockIdx.x * CHUNK;
    const int cnt = min(CHUNK, E - cbase);
    const int tid = threadIdx.x;
    for (int i = tid; i < 512; i += 256) hist[i] = 0;
    __syncthreads();
    for (int k = tid; k < cnt; k += 256)
        atomicAdd(&hist[dstA[cbase + k] >> BSH], 1u);
    __syncthreads();
    for (int i = tid; i < NB; i += 256) {
        unsigned h = hist[i];
        bofs[i] = h ? atomicAdd(&cursor[(size_t)side * NB + i], h) : 0u;
        hist[i] = 0;
    }
    __syncthreads();
    unsigned* pt = part + (size_t)side * E;
    for (int k = tid; k < cnt; k += 256) {
        int s = srcA[cbase + k];
        int d = dstA[cbase + k];
        int b = d >> BSH;
        unsigned pos = bofs[b] + atomicAdd(&hist[b], 1u);
        pt[pos] = ((unsigned)s << BSH) | (unsigned)(d & (BNODES - 1));
    }
}

// ---------------- bucket accumulate: LDS accx over 256-node range -----------
// 512 threads, 32 lanes/edge, 1 float/lane: LDS-atomic banks 0..31, 2
// lanes/bank (free per m136); gather = 128B coalesced per edge.
__global__ void k_bucket(const unsigned* __restrict__ bstart,
                         const unsigned* __restrict__ part,
                         const float* __restrict__ xs,
                         float* __restrict__ accx, int N, int E, int NB) {
    __shared__ float sacc[BNODES * FIN];   // 32 KB
    const int side = blockIdx.y;
    const int b = blockIdx.x;
    const int base = b * BNODES;
    const int tid = threadIdx.x;
    const float* xsS = xs + (size_t)side * N * FIN;

    for (int idx = tid; idx < BNODES * 8; idx += 512) {
        int n = idx >> 3, q = idx & 7;
        float4 v = make_float4(0.f, 0.f, 0.f, 0.f);
        if (base + n < N) v = *(const float4*)(xsS + (size_t)(base + n) * FIN + q * 4);
        *(float4*)&sacc[n * FIN + q * 4] = v;
    }
    __syncthreads();

    unsigned js = bstart[(size_t)side * (NB + 1) + b];
    unsigned je = bstart[(size_t)side * (NB + 1) + b + 1];
    const unsigned* pt = part + (size_t)side * E;
    int q = tid & 31;
    for (unsigned j = js + (tid >> 5); j < je; j += 16) {
        unsigned p = pt[j];
        unsigned s = p >> BSH, d = p & (BNODES - 1);
        float v = xsS[(size_t)s * FIN + q];
        atomicAdd(&sacc[d * FIN + q], v);
    }
    __syncthreads();

    int nn = min(BNODES, N - base);
    float* ax = accx + (size_t)side * N * FIN;
    for (int idx = tid; idx < nn * 8; idx += 512) {
        int n = idx >> 3, qq = idx & 7;
        *(float4*)(ax + (size_t)(base + n) * FIN + qq * 4) = *(float4*)&sacc[n * FIN + qq * 4];
    }
}

// ---------------- node out: y = relu(dinv*(accx@W)+b); pool atomics ---------
__global__ void k_nodeout(const float* __restrict__ accx, const float* __restrict__ dinv,
                          const int* __restrict__ b1, const int* __restrict__ b2,
                          const float* __restrict__ Wc, const float* __restrict__ bc,
                          float* __restrict__ gsum, float* __restrict__ gcnt, int N) {
    __shared__ float sW[FIN * FOUT];
    __shared__ float sA[4][FIN];
    const int side = blockIdx.y;
    const int* batch = side ? b2 : b1;
    int tid = threadIdx.x;
    for (int i = tid; i < FIN * FOUT; i += 256) sW[i] = Wc[i];
    int n0 = blockIdx.x * 4;
    if (tid < 128) {
        int nn = n0 + (tid >> 5);
        int f = tid & 31;
        sA[tid >> 5][f] = (nn < N) ? accx[((size_t)side * N + nn) * FIN + f] : 0.f;
    }
    __syncthreads();
    int local = tid >> 6;        // node within block, 0..3
    int f = tid & 63;            // output feature
    int n = n0 + local;
    if (n < N) {
        float acc = 0.f;
#pragma unroll
        for (int i = 0; i < FIN; i++) acc += sA[local][i] * sW[i * FOUT + f];
        float y = fmaxf(dinv[(size_t)side * N + n] * acc + bc[f], 0.f);
        int b = batch[n];
        atomicAdd(&gsum[(((size_t)side * NG) + b) * FOUT + f], y);
        if (f == 0) atomicAdd(&gcnt[(size_t)side * NG + b], 1.f);
    }
}

// ---------------- MLP head: 128->64->32->16->1 + sigmoid --------------------
__global__ void k_mlp(const float* __restrict__ gsum, const float* __restrict__ gcnt,
                      const float* __restrict__ W1, const float* __restrict__ bb1,
                      const float* __restrict__ W2, const float* __restrict__ bb2,
                      const float* __restrict__ W3, const float* __restrict__ bb3,
                      const float* __restrict__ W4, const float* __restrict__ bb4,
                      float* __restrict__ out) {
    __shared__ float h[128], h1[64], h2[32], h3[16];
    int g = blockIdx.x, tid = threadIdx.x;
    int side = tid >> 6, f = tid & 63;
    float c = fmaxf(gcnt[(size_t)side * NG + g], 1.f);
    h[tid] = gsum[(((size_t)side * NG) + g) * FOUT + f] / c;
    __syncthreads();
    if (tid < 64) {
        float a = bb1[tid];
#pragma unroll 8
        for (int i = 0; i < 128; i++) a += h[i] * W1[i * 64 + tid];
        h1[tid] = fmaxf(a, 0.f);
    }
    __syncthreads();
    if (tid < 32) {
        float a = bb2[tid];
#pragma unroll 8
        for (int i = 0; i < 64; i++) a += h1[i] * W2[i * 32 + tid];
        h2[tid] = fmaxf(a, 0.f);
    }
    __syncthreads();
    if (tid < 16) {
        float a = bb3[tid];
#pragma unroll 8
        for (int i = 0; i < 32; i++) a += h2[i] * W3[i * 16 + tid];
        h3[tid] = fmaxf(a, 0.f);
    }
    __syncthreads();
    if (tid == 0) {
        float a = bb4[0];
#pragma unroll
        for (int i = 0; i < 16; i++) a += h3[i] * W4[i];
        out[g] = 1.f / (1.f + expf(-a));
    }
}

extern "C" void kernel_launch(void* const* d_in, const int* in_sizes, int n_in,
                              void* d_out, int out_size, void* d_ws, size_t ws_size,
                              hipStream_t stream) {
    const float* x1  = (const float*)d_in[0];
    const int*   ei1 = (const int*)d_in[1];
    const int*   bt1 = (const int*)d_in[2];
    const float* x2  = (const float*)d_in[3];
    const int*   ei2 = (const int*)d_in[4];
    const int*   bt2 = (const int*)d_in[5];
    const float* Wc  = (const float*)d_in[6];
    const float* bc  = (const float*)d_in[7];
    const float* W1  = (const float*)d_in[8];
    const float* bb1 = (const float*)d_in[9];
    const float* W2  = (const float*)d_in[10];
    const float* bb2 = (const float*)d_in[11];
    const float* W3  = (const float*)d_in[12];
    const float* bb3 = (const float*)d_in[13];
    const float* W4  = (const float*)d_in[14];
    const float* bb4 = (const float*)d_in[15];

    const int N = in_sizes[0] / FIN;     // 100000
    const int E = in_sizes[1] / 2;       // 1600000
    const int NB = (N + BNODES - 1) >> BSH;   // 391 buckets/side

    // workspace layout (4-byte units):
    // deg(2N) | gsum(2*NG*64) | gcnt(2*NG)   <-- zeroed
    // dinv(2N) | xs(64N) | accx(64N) | bsum(2NB) | bstart(2(NB+1)) | cursor(2NB) | part(2E)
    unsigned* deg = (unsigned*)d_ws;
    float* gsum = (float*)(deg + 2 * (size_t)N);
    float* gcnt = gsum + 2 * (size_t)NG * FOUT;
    float* dinv = gcnt + 2 * (size_t)NG;
    float* xs   = dinv + 2 * (size_t)N;
    float* accx = xs + 2 * (size_t)N * FIN;
    unsigned* bsum   = (unsigned*)(accx + 2 * (size_t)N * FIN);
    unsigned* bstart = bsum + 2 * (size_t)NB;
    unsigned* cursor = bstart + 2 * (size_t)(NB + 1);
    unsigned* part   = cursor + 2 * (size_t)NB;

    size_t zbytes = (2 * (size_t)N + 2 * (size_t)NG * FOUT + 2 * (size_t)NG) * 4;
    hipMemsetAsync(d_ws, 0, zbytes, stream);

    dim3 blk(256);
    k_degree<<<dim3((E + 255) / 256, 2), blk, 0, stream>>>(ei1, ei2, E, deg, N);
    k_bsum  <<<dim3(NB, 2), blk, 0, stream>>>(deg, bsum, N, NB);
    k_bscan <<<dim3(2), blk, 0, stream>>>(bsum, bstart, cursor, NB);
    k_prep  <<<dim3((N * 8 + 255) / 256, 2), blk, 0, stream>>>(x1, x2, deg, dinv, xs, N);
    k_part2 <<<dim3((E + CHUNK - 1) / CHUNK, 2), blk, 0, stream>>>(ei1, ei2, E, cursor, part, NB);
    k_bucket<<<dim3(NB, 2), dim3(512), 0, stream>>>(bstart, part, xs, accx, N, E, NB);
    k_nodeout<<<dim3((N + 3) / 4, 2), blk, 0, stream>>>(accx, dinv, bt1, bt2, Wc, bc, gsum, gcnt, N);
    k_mlp<<<NG, 128, 0, stream>>>(gsum, gcnt, W1, bb1, W2, bb2, W3, bb3, W4, bb4, (float*)d_out);
}

// Round 10
// 1189.525 us; speedup vs baseline: 1.7877x; 1.0005x over previous
//
#include <hip/hip_runtime.h>
#include <math.h>

#define NG 1024   // graphs per side
#define FIN 32
#define FOUT 64
#define BSH 8                 // bucket shift: 256 nodes per bucket
#define BNODES 256
#define CHUNK 8192            // edges per k_part2 block

// ---------------- degree: deg[dst] += 1 per edge (self-loop added later) ----
__global__ void k_degree(const int* __restrict__ ei1, const int* __restrict__ ei2,
                         int E, unsigned* __restrict__ deg, int N) {
    const int side = blockIdx.y;
    const int* ei = side ? ei2 : ei1;
    unsigned* d = deg + (size_t)side * N;
    int e = blockIdx.x * blockDim.x + threadIdx.x;
    if (e < E) atomicAdd(&d[ei[E + e]], 1u);
}

// ---------------- bucket sums: bsum[b] = sum(deg[b*256 .. b*256+255]) -------
__global__ void k_bsum(const unsigned* __restrict__ deg,
                       unsigned* __restrict__ bsum, int N, int NB) {
    const int side = blockIdx.y;
    int b = blockIdx.x;
    int n = b * BNODES + threadIdx.x;
    unsigned d = (n < N) ? deg[(size_t)side * N + n] : 0u;
    for (int off = 32; off; off >>= 1) d += __shfl_down(d, off);
    __shared__ unsigned red[4];
    int w = threadIdx.x >> 6;
    if ((threadIdx.x & 63) == 0) red[w] = d;
    __syncthreads();
    if (threadIdx.x == 0)
        bsum[(size_t)side * NB + b] = red[0] + red[1] + red[2] + red[3];
}

// ---------------- scan bucket sums -> bstart (NB+1), cursor -----------------
__global__ void k_bscan(const unsigned* __restrict__ bsum,
                        unsigned* __restrict__ bstart,
                        unsigned* __restrict__ cursor, int NB) {
    const int side = blockIdx.x;
    __shared__ unsigned s[512];
    int tid = threadIdx.x;
    for (int i = tid; i < 512; i += 256)
        s[i] = (i < NB) ? bsum[(size_t)side * NB + i] : 0u;
    __syncthreads();
    for (int off = 1; off < 512; off <<= 1) {
        unsigned a0 = (tid >= off) ? s[tid - off] : 0u;
        unsigned a1 = (tid + 256 >= off) ? s[tid + 256 - off] : 0u;
        unsigned b0 = s[tid], b1 = s[tid + 256];
        __syncthreads();
        s[tid] = b0 + a0; s[tid + 256] = b1 + a1;
        __syncthreads();
    }
    for (int i = tid; i <= NB; i += 256) {
        unsigned excl = (i == 0) ? 0u : s[i - 1];
        bstart[(size_t)side * (NB + 1) + i] = excl;
        if (i < NB) cursor[(size_t)side * NB + i] = excl;
    }
}

// ---------------- prep: dinv = rsqrt(deg+1); xs = x*dinv --------------------
__global__ void k_prep(const float* __restrict__ x1, const float* __restrict__ x2,
                       const unsigned* __restrict__ deg,
                       float* __restrict__ dinv, float* __restrict__ xs, int N) {
    const int side = blockIdx.y;
    const float* x = side ? x2 : x1;
    int t = blockIdx.x * blockDim.x + threadIdx.x;   // n*8 + q
    int n = t >> 3, q = t & 7;
    if (n >= N) return;
    float di = rsqrtf((float)(deg[(size_t)side * N + n] + 1u));
    if (q == 0) dinv[(size_t)side * N + n] = di;
    size_t base = ((size_t)side * N + n) * FIN + q * 4;
    float4 v = *(const float4*)(x + (size_t)n * FIN + q * 4);
    v.x *= di; v.y *= di; v.z *= di; v.w *= di;
    *(float4*)(xs + base) = v;
}

// ---------------- partition, block-aggregated (LDS-staged binning) ----------
__global__ void k_part2(const int* __restrict__ ei1, const int* __restrict__ ei2,
                        int E, unsigned* __restrict__ cursor,
                        unsigned* __restrict__ part, int NB) {
    __shared__ unsigned hist[512];
    __shared__ unsigned bofs[512];
    const int side = blockIdx.y;
    const int* ei = side ? ei2 : ei1;
    const int* srcA = ei;
    const int* dstA = ei + E;
    const int cbase = blockIdx.x * CHUNK;
    const int cnt = min(CHUNK, E - cbase);
    const int tid = threadIdx.x;
    for (int i = tid; i < 512; i += 256) hist[i] = 0;
    __syncthreads();
    for (int k = tid; k < cnt; k += 256)
        atomicAdd(&hist[dstA[cbase + k] >> BSH], 1u);
    __syncthreads();
    for (int i = tid; i < NB; i += 256) {
        unsigned h = hist[i];
        bofs[i] = h ? atomicAdd(&cursor[(size_t)side * NB + i], h) : 0u;
        hist[i] = 0;
    }
    __syncthreads();
    unsigned* pt = part + (size_t)side * E;
    for (int k = tid; k < cnt; k += 256) {
        int s = srcA[cbase + k];
        int d = dstA[cbase + k];
        int b = d >> BSH;
        unsigned pos = bofs[b] + atomicAdd(&hist[b], 1u);
        pt[pos] = ((unsigned)s << BSH) | (unsigned)(d & (BNODES - 1));
    }
}

// ---------------- bucket accumulate: LDS accx over 256-node range -----------
// 512 threads, 32 lanes/edge, 1 float/lane. 8-wide unrolled gather: 8
// independent pt loads then 8 independent xs gathers in flight per lane
// (latency-bound fix, round-9 postmortem: serial dep-chain gave 291 GB/s).
__global__ void k_bucket(const unsigned* __restrict__ bstart,
                         const unsigned* __restrict__ part,
                         const float* __restrict__ xs,
                         float* __restrict__ accx, int N, int E, int NB) {
    __shared__ float sacc[BNODES * FIN];   // 32 KB
    const int side = blockIdx.y;
    const int b = blockIdx.x;
    const int base = b * BNODES;
    const int tid = threadIdx.x;
    const float* xsS = xs + (size_t)side * N * FIN;

    for (int idx = tid; idx < BNODES * 8; idx += 512) {
        int n = idx >> 3, q = idx & 7;
        float4 v = make_float4(0.f, 0.f, 0.f, 0.f);
        if (base + n < N) v = *(const float4*)(xsS + (size_t)(base + n) * FIN + q * 4);
        *(float4*)&sacc[n * FIN + q * 4] = v;
    }
    __syncthreads();

    const unsigned js = bstart[(size_t)side * (NB + 1) + b];
    const unsigned je = bstart[(size_t)side * (NB + 1) + b + 1];
    const unsigned* pt = part + (size_t)side * E;
    const int q = tid & 31;
    const int lane_e = tid >> 5;          // 0..15
    const int STR = 16;                   // edges in flight per iter step

    unsigned j = js + lane_e;
    // 8-wide unroll: 8 pt loads -> 8 gathers -> 8 LDS atomics
    for (; j + 7 * STR < je; j += 8 * STR) {
        unsigned p0 = pt[j];
        unsigned p1 = pt[j + STR];
        unsigned p2 = pt[j + 2 * STR];
        unsigned p3 = pt[j + 3 * STR];
        unsigned p4 = pt[j + 4 * STR];
        unsigned p5 = pt[j + 5 * STR];
        unsigned p6 = pt[j + 6 * STR];
        unsigned p7 = pt[j + 7 * STR];
        float v0 = xsS[(size_t)(p0 >> BSH) * FIN + q];
        float v1 = xsS[(size_t)(p1 >> BSH) * FIN + q];
        float v2 = xsS[(size_t)(p2 >> BSH) * FIN + q];
        float v3 = xsS[(size_t)(p3 >> BSH) * FIN + q];
        float v4 = xsS[(size_t)(p4 >> BSH) * FIN + q];
        float v5 = xsS[(size_t)(p5 >> BSH) * FIN + q];
        float v6 = xsS[(size_t)(p6 >> BSH) * FIN + q];
        float v7 = xsS[(size_t)(p7 >> BSH) * FIN + q];
        atomicAdd(&sacc[(p0 & (BNODES - 1)) * FIN + q], v0);
        atomicAdd(&sacc[(p1 & (BNODES - 1)) * FIN + q], v1);
        atomicAdd(&sacc[(p2 & (BNODES - 1)) * FIN + q], v2);
        atomicAdd(&sacc[(p3 & (BNODES - 1)) * FIN + q], v3);
        atomicAdd(&sacc[(p4 & (BNODES - 1)) * FIN + q], v4);
        atomicAdd(&sacc[(p5 & (BNODES - 1)) * FIN + q], v5);
        atomicAdd(&sacc[(p6 & (BNODES - 1)) * FIN + q], v6);
        atomicAdd(&sacc[(p7 & (BNODES - 1)) * FIN + q], v7);
    }
    for (; j < je; j += STR) {
        unsigned p = pt[j];
        float v = xsS[(size_t)(p >> BSH) * FIN + q];
        atomicAdd(&sacc[(p & (BNODES - 1)) * FIN + q], v);
    }
    __syncthreads();

    int nn = min(BNODES, N - base);
    float* ax = accx + (size_t)side * N * FIN;
    for (int idx = tid; idx < nn * 8; idx += 512) {
        int n = idx >> 3, qq = idx & 7;
        *(float4*)(ax + (size_t)(base + n) * FIN + qq * 4) = *(float4*)&sacc[n * FIN + qq * 4];
    }
}

// ---------------- node out: y = relu(dinv*(accx@W)+b); pool atomics ---------
__global__ void k_nodeout(const float* __restrict__ accx, const float* __restrict__ dinv,
                          const int* __restrict__ b1, const int* __restrict__ b2,
                          const float* __restrict__ Wc, const float* __restrict__ bc,
                          float* __restrict__ gsum, float* __restrict__ gcnt, int N) {
    __shared__ float sW[FIN * FOUT];
    __shared__ float sA[4][FIN];
    const int side = blockIdx.y;
    const int* batch = side ? b2 : b1;
    int tid = threadIdx.x;
    for (int i = tid; i < FIN * FOUT; i += 256) sW[i] = Wc[i];
    int n0 = blockIdx.x * 4;
    if (tid < 128) {
        int nn = n0 + (tid >> 5);
        int f = tid & 31;
        sA[tid >> 5][f] = (nn < N) ? accx[((size_t)side * N + nn) * FIN + f] : 0.f;
    }
    __syncthreads();
    int local = tid >> 6;        // node within block, 0..3
    int f = tid & 63;            // output feature
    int n = n0 + local;
    if (n < N) {
        float acc = 0.f;
#pragma unroll
        for (int i = 0; i < FIN; i++) acc += sA[local][i] * sW[i * FOUT + f];
        float y = fmaxf(dinv[(size_t)side * N + n] * acc + bc[f], 0.f);
        int b = batch[n];
        atomicAdd(&gsum[(((size_t)side * NG) + b) * FOUT + f], y);
        if (f == 0) atomicAdd(&gcnt[(size_t)side * NG + b], 1.f);
    }
}

// ---------------- MLP head: 128->64->32->16->1 + sigmoid --------------------
__global__ void k_mlp(const float* __restrict__ gsum, const float* __restrict__ gcnt,
                      const float* __restrict__ W1, const float* __restrict__ bb1,
                      const float* __restrict__ W2, const float* __restrict__ bb2,
                      const float* __restrict__ W3, const float* __restrict__ bb3,
                      const float* __restrict__ W4, const float* __restrict__ bb4,
                      float* __restrict__ out) {
    __shared__ float h[128], h1[64], h2[32], h3[16];
    int g = blockIdx.x, tid = threadIdx.x;
    int side = tid >> 6, f = tid & 63;
    float c = fmaxf(gcnt[(size_t)side * NG + g], 1.f);
    h[tid] = gsum[(((size_t)side * NG) + g) * FOUT + f] / c;
    __syncthreads();
    if (tid < 64) {
        float a = bb1[tid];
#pragma unroll 8
        for (int i = 0; i < 128; i++) a += h[i] * W1[i * 64 + tid];
        h1[tid] = fmaxf(a, 0.f);
    }
    __syncthreads();
    if (tid < 32) {
        float a = bb2[tid];
#pragma unroll 8
        for (int i = 0; i < 64; i++) a += h1[i] * W2[i * 32 + tid];
        h2[tid] = fmaxf(a, 0.f);
    }
    __syncthreads();
    if (tid < 16) {
        float a = bb3[tid];
#pragma unroll 8
        for (int i = 0; i < 32; i++) a += h2[i] * W3[i * 16 + tid];
        h3[tid] = fmaxf(a, 0.f);
    }
    __syncthreads();
    if (tid == 0) {
        float a = bb4[0];
#pragma unroll
        for (int i = 0; i < 16; i++) a += h3[i] * W4[i];
        out[g] = 1.f / (1.f + expf(-a));
    }
}

extern "C" void kernel_launch(void* const* d_in, const int* in_sizes, int n_in,
                              void* d_out, int out_size, void* d_ws, size_t ws_size,
                              hipStream_t stream) {
    const float* x1  = (const float*)d_in[0];
    const int*   ei1 = (const int*)d_in[1];
    const int*   bt1 = (const int*)d_in[2];
    const float* x2  = (const float*)d_in[3];
    const int*   ei2 = (const int*)d_in[4];
    const int*   bt2 = (const int*)d_in[5];
    const float* Wc  = (const float*)d_in[6];
    const float* bc  = (const float*)d_in[7];
    const float* W1  = (const float*)d_in[8];
    const float* bb1 = (const float*)d_in[9];
    const float* W2  = (const float*)d_in[10];
    const float* bb2 = (const float*)d_in[11];
    const float* W3  = (const float*)d_in[12];
    const float* bb3 = (const float*)d_in[13];
    const float* W4  = (const float*)d_in[14];
    const float* bb4 = (const float*)d_in[15];

    const int N = in_sizes[0] / FIN;     // 100000
    const int E = in_sizes[1] / 2;       // 1600000
    const int NB = (N + BNODES - 1) >> BSH;   // 391 buckets/side

    // workspace layout (4-byte units):
    // deg(2N) | gsum(2*NG*64) | gcnt(2*NG)   <-- zeroed
    // dinv(2N) | xs(64N) | accx(64N) | bsum(2NB) | bstart(2(NB+1)) | cursor(2NB) | part(2E)
    unsigned* deg = (unsigned*)d_ws;
    float* gsum = (float*)(deg + 2 * (size_t)N);
    float* gcnt = gsum + 2 * (size_t)NG * FOUT;
    float* dinv = gcnt + 2 * (size_t)NG;
    float* xs   = dinv + 2 * (size_t)N;
    float* accx = xs + 2 * (size_t)N * FIN;
    unsigned* bsum   = (unsigned*)(accx + 2 * (size_t)N * FIN);
    unsigned* bstart = bsum + 2 * (size_t)NB;
    unsigned* cursor = bstart + 2 * (size_t)(NB + 1);
    unsigned* part   = cursor + 2 * (size_t)NB;

    size_t zbytes = (2 * (size_t)N + 2 * (size_t)NG * FOUT + 2 * (size_t)NG) * 4;
    hipMemsetAsync(d_ws, 0, zbytes, stream);

    dim3 blk(256);
    k_degree<<<dim3((E + 255) / 256, 2), blk, 0, stream>>>(ei1, ei2, E, deg, N);
    k_bsum  <<<dim3(NB, 2), blk, 0, stream>>>(deg, bsum, N, NB);
    k_bscan <<<dim3(2), blk, 0, stream>>>(bsum, bstart, cursor, NB);
    k_prep  <<<dim3((N * 8 + 255) / 256, 2), blk, 0, stream>>>(x1, x2, deg, dinv, xs, N);
    k_part2 <<<dim3((E + CHUNK - 1) / CHUNK, 2), blk, 0, stream>>>(ei1, ei2, E, cursor, part, NB);
    k_bucket<<<dim3(NB, 2), dim3(512), 0, stream>>>(bstart, part, xs, accx, N, E, NB);
    k_nodeout<<<dim3((N + 3) / 4, 2), blk, 0, stream>>>(accx, dinv, bt1, bt2, Wc, bc, gsum, gcnt, N);
    k_mlp<<<NG, 128, 0, stream>>>(gsum, gcnt, W1, bb1, W2, bb2, W3, bb3, W4, bb4, (float*)d_out);
}